// Round 4
// baseline (270.384 us; speedup 1.0000x reference)
//
#include <hip/hip_runtime.h>

#define T_LEN  1048576
#define NROWS  32
#define NTAPS  128
#define N2     32
#define BLOCK  256
#define TPW    2              /* 32x32 tiles per wave */
#define NOUT   8192           /* outputs per block = 4 waves * 2 tiles * 1024 */
#define NCH    10             /* K chunks of 16: band k in [0,160) */

typedef __attribute__((ext_vector_type(8)))  _Float16 half8;
typedef __attribute__((ext_vector_type(2)))  __fp16   fp16x2;
typedef __attribute__((ext_vector_type(16))) float    f32x16;

// ---- kernel 1: impulse response h[0..127] (+D at 0); fp16 Toeplitz A-frags ----
// A_c[m,s] = h[m + 127 - 16c - s], lane=(m=lane&31, g=lane>>5), s=8g+i
__global__ __launch_bounds__(NTAPS) void ssm_taps(
    const float* __restrict__ w_real, const float* __restrict__ w_imag,
    const float* __restrict__ log_dt,
    const float* __restrict__ C_real, const float* __restrict__ C_imag,
    const float* __restrict__ B_real, const float* __restrict__ B_imag,
    const float* __restrict__ Dp, float* __restrict__ ws) {
  __shared__ float hsh[NTAPS];
  const int k = threadIdx.x;                 // 0..127
  const float dt = expf(log_dt[0]);
  const float kf = (float)k;
  float acc = 0.f;
  for (int n = 0; n < N2; ++n) {
    const float a  = dt * w_real[n];
    const float b  = dt * w_imag[n];
    const float cr = C_real[n], ci = C_imag[n];
    const float br = B_real[n], bi = B_imag[n];
    const float coef_r = cr * br - ci * bi;
    const float coef_i = cr * bi + ci * br;
    const float e = expf(a * kf);
    float s, c;
    sincosf(b * kf, &s, &c);
    acc += e * (coef_r * c - coef_i * s);
  }
  if (k == 0) acc += Dp[0];
  ws[k]  = acc;                              // plain h (fix kernel)
  hsh[k] = acc;
  __syncthreads();
  if (k < 64) {
    _Float16* AH = (_Float16*)(ws + NTAPS);
    const int m = k & 31, g = k >> 5;
    for (int c = 0; c < NCH; ++c)
      for (int i = 0; i < 8; ++i) {
        const int idx = m + 127 - 16 * c - 8 * g - i;
        const float v = (idx >= 0 && idx < NTAPS) ? hsh[idx] : 0.f;
        AH[(c * 64 + k) * 8 + i] = (_Float16)v;   // RNE
      }
  }
}

// fp16 hi/lo split of 2 floats, packed into words of H/L
__device__ __forceinline__ void cvt_pair(float a, float b, unsigned& H, unsigned& L) {
  fp16x2 h = __builtin_amdgcn_cvt_pkrtz(a, b);
  const float ra = a - (float)h[0];
  const float rb = b - (float)h[1];
  fp16x2 l = __builtin_amdgcn_cvt_pkrtz(ra, rb);
  H = __builtin_bit_cast(unsigned, h);
  L = __builtin_bit_cast(unsigned, l);
}

// ---- kernel 2: implicit-GEMM FIR, no LDS, no barriers ----
__global__ __launch_bounds__(BLOCK, 4) void ssm_conv(
    const float* __restrict__ x, const float* __restrict__ ws,
    float* __restrict__ out) {
  const int tid  = threadIdx.x;
  const int lane = tid & 63;
  const int wid  = tid >> 6;
  const int row  = blockIdx.y;
  const int n0   = blockIdx.x * NOUT;
  const int p = lane & 31, g = lane >> 5;
  const float* __restrict__ xrow = x + (size_t)row * T_LEN;
  const half8* __restrict__ wsA = (const half8*)(ws + NTAPS);

  const int base = n0 - 254 + wid * (TPW * 1024) + 32 * p + 8 * g;
  f32x16 acc0 = {}, acc1 = {};

  if (blockIdx.x != 0) {
#pragma unroll
    for (int c = 0; c < NCH; ++c) {
      const half8 A = wsA[c * 64 + lane];
      {
        const float2* q = (const float2*)(xrow + base + 16 * c);   // 8B-aligned
        const float2 q0 = q[0], q1 = q[1], q2 = q[2], q3 = q[3];
        union { half8 h8; unsigned u[4]; } bh, bl;
        cvt_pair(q0.x, q0.y, bh.u[0], bl.u[0]);
        cvt_pair(q1.x, q1.y, bh.u[1], bl.u[1]);
        cvt_pair(q2.x, q2.y, bh.u[2], bl.u[2]);
        cvt_pair(q3.x, q3.y, bh.u[3], bl.u[3]);
        acc0 = __builtin_amdgcn_mfma_f32_32x32x16_f16(A, bh.h8, acc0, 0, 0, 0);
        acc0 = __builtin_amdgcn_mfma_f32_32x32x16_f16(A, bl.h8, acc0, 0, 0, 0);
      }
      {
        const float2* q = (const float2*)(xrow + base + 1024 + 16 * c);
        const float2 q0 = q[0], q1 = q[1], q2 = q[2], q3 = q[3];
        union { half8 h8; unsigned u[4]; } bh, bl;
        cvt_pair(q0.x, q0.y, bh.u[0], bl.u[0]);
        cvt_pair(q1.x, q1.y, bh.u[1], bl.u[1]);
        cvt_pair(q2.x, q2.y, bh.u[2], bl.u[2]);
        cvt_pair(q3.x, q3.y, bh.u[3], bl.u[3]);
        acc1 = __builtin_amdgcn_mfma_f32_32x32x16_f16(A, bh.h8, acc1, 0, 0, 0);
        acc1 = __builtin_amdgcn_mfma_f32_32x32x16_f16(A, bl.h8, acc1, 0, 0, 0);
      }
    }
  } else {
    // left-edge block: per-element guarded loads (zero-pad x<0)
#pragma unroll
    for (int c = 0; c < NCH; ++c) {
      const half8 A = wsA[c * 64 + lane];
#pragma unroll
      for (int tt = 0; tt < TPW; ++tt) {
        const int e0 = base + tt * 1024 + 16 * c;
        float v[8];
#pragma unroll
        for (int i = 0; i < 8; ++i) {
          const int gi = e0 + i;
          v[i] = (gi >= 0) ? xrow[gi] : 0.f;
        }
        union { half8 h8; unsigned u[4]; } bh, bl;
        cvt_pair(v[0], v[1], bh.u[0], bl.u[0]);
        cvt_pair(v[2], v[3], bh.u[1], bl.u[1]);
        cvt_pair(v[4], v[5], bh.u[2], bl.u[2]);
        cvt_pair(v[6], v[7], bh.u[3], bl.u[3]);
        if (tt == 0) {
          acc0 = __builtin_amdgcn_mfma_f32_32x32x16_f16(A, bh.h8, acc0, 0, 0, 0);
          acc0 = __builtin_amdgcn_mfma_f32_32x32x16_f16(A, bl.h8, acc0, 0, 0, 0);
        } else {
          acc1 = __builtin_amdgcn_mfma_f32_32x32x16_f16(A, bh.h8, acc1, 0, 0, 0);
          acc1 = __builtin_amdgcn_mfma_f32_32x32x16_f16(A, bl.h8, acc1, 0, 0, 0);
        }
      }
    }
  }

  // epilogue: C/D map row m=(r&3)+8*(r>>2)+4g, col nn=p; out = tb + m + 32*nn.
  // reg-quads r=4k..4k+3 are contiguous in m -> direct float4 stores.
  float* __restrict__ orow =
      out + (size_t)row * T_LEN + n0 + wid * (TPW * 1024) + 32 * p + 4 * g;
#pragma unroll
  for (int k = 0; k < 4; ++k) {
    float4 v0, v1;
    v0.x = acc0[4 * k]; v0.y = acc0[4 * k + 1];
    v0.z = acc0[4 * k + 2]; v0.w = acc0[4 * k + 3];
    v1.x = acc1[4 * k]; v1.y = acc1[4 * k + 1];
    v1.z = acc1[4 * k + 2]; v1.w = acc1[4 * k + 3];
    *(float4*)(orow + 8 * k) = v0;
    *(float4*)(orow + 1024 + 8 * k) = v1;
  }
}

// ---- kernel 3: wraparound fixup for n in [0,126] (fp32 exact) ----
__global__ __launch_bounds__(NTAPS) void ssm_fix(
    const float* __restrict__ x, const float* __restrict__ ws,
    float* __restrict__ out) {
  const int row = blockIdx.x;
  const int n = threadIdx.x;
  if (n >= NTAPS - 1) return;
  const float* __restrict__ h = ws;          // plain h at ws[0..127]
  const float* __restrict__ xrow = x + (size_t)row * T_LEN;
  float acc = 0.f;
  for (int k = n + 1; k < NTAPS; ++k)
    acc += h[k] * xrow[T_LEN + n - k];
  out[(size_t)row * T_LEN + n] = acc;
}

extern "C" void kernel_launch(void* const* d_in, const int* in_sizes, int n_in,
                              void* d_out, int out_size, void* d_ws, size_t ws_size,
                              hipStream_t stream) {
  const float* x      = (const float*)d_in[0];
  const float* w_real = (const float*)d_in[1];
  const float* w_imag = (const float*)d_in[2];
  const float* log_dt = (const float*)d_in[3];
  const float* C_real = (const float*)d_in[4];
  const float* C_imag = (const float*)d_in[5];
  const float* B_real = (const float*)d_in[6];
  const float* B_imag = (const float*)d_in[7];
  const float* Dp     = (const float*)d_in[8];
  float* out = (float*)d_out;
  float* ws  = (float*)d_ws;   // 128 f32 h + NCH*64*8 fp16 A-frags = 10.8 KB

  ssm_taps<<<1, NTAPS, 0, stream>>>(w_real, w_imag, log_dt,
                                    C_real, C_imag, B_real, B_imag, Dp, ws);
  dim3 grid(T_LEN / NOUT, NROWS);
  ssm_conv<<<grid, BLOCK, 0, stream>>>(x, ws, out);
  ssm_fix<<<NROWS, NTAPS, 0, stream>>>(x, ws, out);
}

// Round 5
// 72.250 us; speedup vs baseline: 3.7424x; 3.7424x over previous
//
#include <hip/hip_runtime.h>

#define T_LEN  1048576
#define NROWS  32
#define NTAPS  128
#define N2     32
#define BLOCK  256
#define SEG    4096           /* outputs per segment */
#define SPB    8              /* segments per block (grid = 32 rows * 32 blocks) */
#define HALO   256            /* staged gi = n0 - HALO + e  (16B-aligned DMA) */
#define NCH    11             /* K chunks of 16: k = m + 129 - 16c - s */
#define STG_CH 1088           /* staged 16B chunks, padded to 64-chunk groups */

typedef __attribute__((ext_vector_type(8)))  _Float16 half8;
typedef __attribute__((ext_vector_type(2)))  __fp16   fp16x2;
typedef __attribute__((ext_vector_type(16))) float    f32x16;

__device__ __forceinline__ int swz(int q) { return q ^ ((q >> 3) & 7); }

__device__ __forceinline__ void gload_lds16(const float* g, float* l) {
  __builtin_amdgcn_global_load_lds(
      (const __attribute__((address_space(1))) void*)g,
      (__attribute__((address_space(3))) void*)l, 16, 0, 0);
}

// ---- kernel 1: impulse response h[0..127] (+D at 0); fp16 Toeplitz A-frags ----
// A_c[m,s] = h[m + 129 - 16c - s], lane=(m=lane&31, g=lane>>5), s=8g+i
__global__ __launch_bounds__(NTAPS) void ssm_taps(
    const float* __restrict__ w_real, const float* __restrict__ w_imag,
    const float* __restrict__ log_dt,
    const float* __restrict__ C_real, const float* __restrict__ C_imag,
    const float* __restrict__ B_real, const float* __restrict__ B_imag,
    const float* __restrict__ Dp, float* __restrict__ ws) {
  __shared__ float hsh[NTAPS];
  const int k = threadIdx.x;                 // 0..127
  const float dt = expf(log_dt[0]);
  const float kf = (float)k;
  float acc = 0.f;
  for (int n = 0; n < N2; ++n) {
    const float a  = dt * w_real[n];
    const float b  = dt * w_imag[n];
    const float cr = C_real[n], ci = C_imag[n];
    const float br = B_real[n], bi = B_imag[n];
    const float coef_r = cr * br - ci * bi;
    const float coef_i = cr * bi + ci * br;
    const float e = expf(a * kf);
    float s, c;
    sincosf(b * kf, &s, &c);
    acc += e * (coef_r * c - coef_i * s);
  }
  if (k == 0) acc += Dp[0];
  ws[k]  = acc;                              // plain h (fix kernel)
  hsh[k] = acc;
  __syncthreads();
  if (k < 64) {
    _Float16* AH = (_Float16*)(ws + NTAPS);
    const int m = k & 31, g = k >> 5;
    for (int c = 0; c < NCH; ++c)
      for (int i = 0; i < 8; ++i) {
        const int idx = m + 129 - 16 * c - 8 * g - i;
        const float v = (idx >= 0 && idx < NTAPS) ? hsh[idx] : 0.f;
        AH[(c * 64 + k) * 8 + i] = (_Float16)v;   // RNE
      }
  }
}

// ---- kernel 2: implicit-GEMM FIR; async-DMA staged fp32 LDS, double-buffered,
//                8 segments per block, single-term fp16 MFMA ----
__global__ __launch_bounds__(BLOCK, 4) void ssm_conv(
    const float* __restrict__ x, const float* __restrict__ ws,
    float* __restrict__ out) {
  __shared__ __align__(16) float lds[2][STG_CH * 4];   // 2 x 17408 B

  const int tid  = threadIdx.x;
  const int lane = tid & 63;
  const int wid  = tid >> 6;
  const int p    = lane & 31, g = lane >> 5;
  const int row  = blockIdx.x >> 5;          // 32 blocks per row
  const int jb   = blockIdx.x & 31;
  const float* __restrict__ xrow = x + (size_t)row * T_LEN;

  // A fragments (block-invariant, L2-hot)
  half8 A[NCH];
  const half8* __restrict__ wsA = (const half8*)(ws + NTAPS);
#pragma unroll
  for (int c = 0; c < NCH; ++c) A[c] = wsA[c * 64 + lane];

  int n0 = jb * (SPB * SEG);

  // stage one segment: linear LDS dest (DMA), sigma-permuted global source.
  auto stage = [&](int b, int sn0) {
#pragma unroll
    for (int j = 0; j < 5; ++j) {
      const int ch = j * 256 + wid * 64 + lane;
      if (ch < STG_CH) {
        const int sq = swz(ch);
        int gfi = sn0 - HALO + 4 * sq;       // 16B-aligned; clamp left edge
        gfi = gfi < 0 ? 0 : gfi;
        gload_lds16(xrow + gfi, &lds[b][(j * 256 + wid * 64) * 4]);
      }
    }
  };

  stage(0, n0);
  asm volatile("s_waitcnt vmcnt(0)" ::: "memory");
  __syncthreads();

  for (int s = 0; s < SPB; ++s) {
    if (s + 1 < SPB) stage((s + 1) & 1, n0 + SEG);   // prefetch (5 loads/wave)

    const float* __restrict__ Bb = lds[s & 1];
    f32x16 acc = {};
#pragma unroll
    for (int c = 0; c < NCH; ++c) {
      const int q0 = wid * 256 + 8 * p + 2 * g + 4 * c;   // 16B chunk idx (even)
      const float4 f0 = *(const float4*)(Bb + (swz(q0) << 2));
      const float4 f1 = *(const float4*)(Bb + (swz(q0 + 1) << 2));
      union { half8 h8; unsigned u[4]; } bu;
      bu.u[0] = __builtin_bit_cast(unsigned, __builtin_amdgcn_cvt_pkrtz(f0.x, f0.y));
      bu.u[1] = __builtin_bit_cast(unsigned, __builtin_amdgcn_cvt_pkrtz(f0.z, f0.w));
      bu.u[2] = __builtin_bit_cast(unsigned, __builtin_amdgcn_cvt_pkrtz(f1.x, f1.y));
      bu.u[3] = __builtin_bit_cast(unsigned, __builtin_amdgcn_cvt_pkrtz(f1.z, f1.w));
      acc = __builtin_amdgcn_mfma_f32_32x32x16_f16(A[c], bu.h8, acc, 0, 0, 0);
    }

    // C/D map: col=p, row m=(r&3)+8*(r>>2)+4g -> reg-quads are m-contiguous
    float* __restrict__ orow =
        out + (size_t)row * T_LEN + n0 + wid * 1024 + 32 * p + 4 * g;
#pragma unroll
    for (int kq = 0; kq < 4; ++kq) {
      float4 v;
      v.x = acc[4 * kq];     v.y = acc[4 * kq + 1];
      v.z = acc[4 * kq + 2]; v.w = acc[4 * kq + 3];
      *(float4*)(orow + 8 * kq) = v;
    }

    if (s + 1 < SPB) {
      // newest 4 outstanding = our stores; this waits only the 5 prefetch loads
      asm volatile("s_waitcnt vmcnt(4)" ::: "memory");
      __syncthreads();
    }
    n0 += SEG;
  }
}

// ---- kernel 3: exact fp32 fixup for n in [0,254) (wraparound + left edge) ----
__global__ __launch_bounds__(BLOCK) void ssm_fix(
    const float* __restrict__ x, const float* __restrict__ ws,
    float* __restrict__ out) {
  const int row = blockIdx.x;
  const int n = threadIdx.x;
  const float* __restrict__ h = ws;
  const float* __restrict__ xrow = x + (size_t)row * T_LEN;
  float acc = 0.f;
  if (n < 127) {                             // circular wraparound region
    for (int k = n + 1; k < NTAPS; ++k)
      acc += h[k] * xrow[T_LEN + n - k];
  } else if (n < 254) {                      // causal with zero left-pad
    for (int k = 0; k <= n - 127; ++k)
      acc += h[k] * xrow[n - 127 - k];
  } else {
    return;
  }
  out[(size_t)row * T_LEN + n] = acc;
}

extern "C" void kernel_launch(void* const* d_in, const int* in_sizes, int n_in,
                              void* d_out, int out_size, void* d_ws, size_t ws_size,
                              hipStream_t stream) {
  const float* x      = (const float*)d_in[0];
  const float* w_real = (const float*)d_in[1];
  const float* w_imag = (const float*)d_in[2];
  const float* log_dt = (const float*)d_in[3];
  const float* C_real = (const float*)d_in[4];
  const float* C_imag = (const float*)d_in[5];
  const float* B_real = (const float*)d_in[6];
  const float* B_imag = (const float*)d_in[7];
  const float* Dp     = (const float*)d_in[8];
  float* out = (float*)d_out;
  float* ws  = (float*)d_ws;   // 128 f32 h + NCH*64*8 fp16 A-frags = 11.8 KB

  ssm_taps<<<1, NTAPS, 0, stream>>>(w_real, w_imag, log_dt,
                                    C_real, C_imag, B_real, B_imag, Dp, ws);
  ssm_conv<<<NROWS * 32, BLOCK, 0, stream>>>(x, ws, out);
  ssm_fix<<<NROWS, BLOCK, 0, stream>>>(x, ws, out);
}